// Round 9
// baseline (343.512 us; speedup 1.0000x reference)
//
#include <hip/hip_runtime.h>
#include <hip/hip_bf16.h>

#define N_    8
#define H_    32
#define W_    32
#define C_    768
#define NH_   12
#define HD_   64
#define B_    96      // N_*NH_
#define HW_   1024
#define C3_   2304
#define SCALE_ 0.125f

typedef __attribute__((ext_vector_type(4))) float f32x4;
typedef __attribute__((ext_vector_type(8))) short s16x8;
typedef __attribute__((ext_vector_type(2))) unsigned int u32x2;
typedef __attribute__((ext_vector_type(4))) unsigned int u32x4;
typedef unsigned short u16;
typedef unsigned int u32;

__device__ inline u16 f2b(float x) {
    __hip_bfloat16 h = __float2bfloat16(x);
    return *reinterpret_cast<u16*>(&h);
}
__device__ inline float b2f(u16 x) {
    u32 u = ((u32)x) << 16;
    return *reinterpret_cast<float*>(&u);
}

__device__ __forceinline__ void gld_lds16(const void* g, void* l) {
    __builtin_amdgcn_global_load_lds(
        (const __attribute__((address_space(1))) u32*)g,
        (__attribute__((address_space(3))) u32*)l, 16, 0, 0);
}

// ---------------------------------------------------------------------------
// convert fp32 -> bf16 (vectorized, grid-stride)
// ---------------------------------------------------------------------------
__global__ __launch_bounds__(256) void cvt_bf16(const float* __restrict__ in,
                                                u16* __restrict__ out, int n4) {
    for (int i = blockIdx.x * blockDim.x + threadIdx.x; i < n4; i += gridDim.x * blockDim.x) {
        float4 v = ((const float4*)in)[i];
        ushort4 o;
        o.x = f2b(v.x); o.y = f2b(v.y); o.z = f2b(v.z); o.w = f2b(v.w);
        ((ushort4*)out)[i] = o;
    }
}

// ---------------------------------------------------------------------------
// transpose-convert: in [K][N] fp32 -> out [N][K] bf16, 64x64 tiles
// ---------------------------------------------------------------------------
__global__ __launch_bounds__(256) void tcvt_bf16(const float* __restrict__ in,
                                                 u16* __restrict__ out, int K, int N) {
    __shared__ u16 tile[64][72];
    const int t = threadIdx.x;
    const int k0 = blockIdx.y * 64, n0 = blockIdx.x * 64;
    const int r = t >> 2, c4 = (t & 3) * 16;
    #pragma unroll
    for (int u = 0; u < 4; ++u) {
        float4 v = *(const float4*)(in + (size_t)(k0 + r) * N + n0 + c4 + u * 4);
        tile[c4 + u*4 + 0][r] = f2b(v.x);
        tile[c4 + u*4 + 1][r] = f2b(v.y);
        tile[c4 + u*4 + 2][r] = f2b(v.z);
        tile[c4 + u*4 + 3][r] = f2b(v.w);
    }
    __syncthreads();
    #pragma unroll
    for (int u = 0; u < 2; ++u) {
        s16x8 v;
        #pragma unroll
        for (int e = 0; e < 8; ++e) v[e] = (short)tile[r][c4 + u*8 + e];
        *(s16x8*)(out + (size_t)(n0 + r) * K + k0 + c4 + u*8) = v;
    }
}

// ---------------------------------------------------------------------------
// MFMA GEMM core (m97-style): 128x128 tile, BK=32, 4 waves 2x2, double-buffered
// LDS via global_load_lds width 16, one barrier per K-step. K = 768.
// ---------------------------------------------------------------------------
#define GEMM_CORE(A_, Bt_)                                                           \
    __shared__ u16 sA[2][128 * 32];                                                  \
    __shared__ u16 sB[2][128 * 32];                                                  \
    const int t = threadIdx.x;                                                       \
    const int lane = t & 63;                                                         \
    const int w = t >> 6;                                                            \
    const int wm = w >> 1, wn = w & 1;                                               \
    const int l15 = lane & 15, lg = lane >> 4;                                       \
    const int nbase = blockIdx.x * 128;                                              \
    const int mbase = blockIdx.y * 128;                                              \
    const int srow = lane >> 2;                                                      \
    const int sslot = lane & 3;                                                      \
    const u16* gA0 = (A_) + (size_t)(mbase + w * 16 + srow) * 768 + sslot * 8;       \
    const u16* gA1 = gA0 + (size_t)64 * 768;                                         \
    const u16* gB0 = (Bt_) + (size_t)(nbase + w * 16 + srow) * 768 + sslot * 8;      \
    const u16* gB1 = gB0 + (size_t)64 * 768;                                         \
    f32x4 acc[4][4] = {};                                                            \
    gld_lds16(gA0, &sA[0][w * 512]);                                                 \
    gld_lds16(gA1, &sA[0][(w + 4) * 512]);                                           \
    gld_lds16(gB0, &sB[0][w * 512]);                                                 \
    gld_lds16(gB1, &sB[0][(w + 4) * 512]);                                           \
    for (int kt = 0; kt < 24; ++kt) {                                                \
        const int p = kt & 1;                                                        \
        __syncthreads();                                                             \
        if (kt < 23) {                                                               \
            const int kb = (kt + 1) * 32;                                            \
            gld_lds16(gA0 + kb, &sA[p ^ 1][w * 512]);                                \
            gld_lds16(gA1 + kb, &sA[p ^ 1][(w + 4) * 512]);                          \
            gld_lds16(gB0 + kb, &sB[p ^ 1][w * 512]);                                \
            gld_lds16(gB1 + kb, &sB[p ^ 1][(w + 4) * 512]);                          \
        }                                                                            \
        const u16* pa = &sA[p][(wm * 64 + l15) * 32 + lg * 8];                       \
        const u16* pb = &sB[p][(wn * 64 + l15) * 32 + lg * 8];                       \
        s16x8 afr[4], bfr[4];                                                        \
        _Pragma("unroll")                                                            \
        for (int i = 0; i < 4; ++i) {                                                \
            afr[i] = *(const s16x8*)(pa + i * 512);                                  \
            bfr[i] = *(const s16x8*)(pb + i * 512);                                  \
        }                                                                            \
        _Pragma("unroll")                                                            \
        for (int i = 0; i < 4; ++i)                                                  \
            _Pragma("unroll")                                                        \
            for (int j = 0; j < 4; ++j)                                              \
                acc[i][j] = __builtin_amdgcn_mfma_f32_16x16x32_bf16(afr[i], bfr[j],  \
                                                                    acc[i][j], 0, 0, 0); \
    }

__global__ __launch_bounds__(256) void gemm_qkv(const u16* __restrict__ A,
                                                const u16* __restrict__ Bt,
                                                const float* __restrict__ bias,
                                                float* __restrict__ qout,
                                                u16* __restrict__ kout,
                                                u16* __restrict__ vout) {
    GEMM_CORE(A, Bt)
    const int which = nbase / C_;
    const int head  = ((nbase % C_) >> 6) + wn;
    const int mrow0 = mbase + wm * 64 + lg * 4;
    #pragma unroll
    for (int i = 0; i < 4; ++i) {
        #pragma unroll
        for (int r = 0; r < 4; ++r) {
            const int m = mrow0 + i * 16 + r;
            const size_t bidx = (size_t)((m >> 10) * NH_ + head);
            const int pp = m & 1023;
            #pragma unroll
            for (int j = 0; j < 4; ++j) {
                const int d = j * 16 + l15;
                const float val = acc[i][j][r] + bias[nbase + wn * 64 + d];
                if (which == 0)      qout[(bidx * HW_ + pp) * HD_ + d] = val;
                else if (which == 1) kout[(bidx * HW_ + pp) * HD_ + d] = f2b(val);
                else                 vout[bidx * (size_t)(HW_ * HD_) + (size_t)d * HW_ + pp] = f2b(val);
            }
        }
    }
}

__global__ __launch_bounds__(256) void gemm_proj(const u16* __restrict__ A,
                                                 const u16* __restrict__ Bt,
                                                 const float* __restrict__ bias,
                                                 float* __restrict__ out) {
    GEMM_CORE(A, Bt)
    const int mrow0 = mbase + wm * 64 + lg * 4;
    #pragma unroll
    for (int i = 0; i < 4; ++i) {
        #pragma unroll
        for (int r = 0; r < 4; ++r) {
            const int m = mrow0 + i * 16 + r;
            #pragma unroll
            for (int j = 0; j < 4; ++j) {
                const int n = nbase + wn * 64 + j * 16 + l15;
                out[(size_t)m * C_ + n] = acc[i][j][r] + bias[n];
            }
        }
    }
}

// ---------------------------------------------------------------------------
// Kernel: MFMA bf16 flash rel-pos attention — occupancy-focused rebuild.
// Round-6 geometry (64 q-rows, 4 waves, swapped QK^T, reg-staged K/V) with:
//  * NO P-LDS round trip: PV A-fragment built in-register via 16 __shfl
//    (ds_bpermute) + 8 selects.  Mapping (verified 3 elements by hand):
//    dest (lg,l15,kvh) needs pw[2kvh + (lg>>1)] from lanes l15+32(lg&1) and
//    +16; select by lg>>1 after the two shfls.
//  * bh bias table stored bf16 [64][34] in LDS (error ~2e-4); bw hoisted to
//    f32 regs from a transient f32 [64][36] table.
//  * Single compute phase per KV tile: QK then PV then B1|swap|B2.
// LDS map (bytes): sBHu[0,4352) bf16[64][34] persistent;
//   sBW[4352,13568) f32[64][36] transient; sK[13568,22784) u16[64][72];
//   sVt[22784,32000) u16[64][72]; qs f32[64][68] @13568 (prologue, overlaps
//   sK/sVt).  total 32000 -> 5 blocks/CU = 20 waves/CU (was 3 blocks).
// __launch_bounds__(256,5): VGPR cap 102.
// ---------------------------------------------------------------------------
__global__ __launch_bounds__(256, 5) void attn_mfma(const float* __restrict__ qf,
                                                    const u16* __restrict__ kbf,
                                                    const u16* __restrict__ vtb,
                                                    const float* __restrict__ rel_h,
                                                    const float* __restrict__ rel_w,
                                                    u16* __restrict__ ob) {
    extern __shared__ char smem[];
    u16*   sBHu = (u16*)smem;                 // [64][34] bf16 (persistent)
    float* sBW  = (float*)(smem + 4352);      // [64][36] f32 (prologue only)
    u16*   sK   = (u16*)(smem + 13568);       // [64][72]
    u16*   sVt  = (u16*)(smem + 22784);       // [64][72]
    float* qs   = (float*)(smem + 13568);     // [64][68] f32 (prologue only)

    const int t = threadIdx.x;
    const int lane = t & 63;
    const int w = t >> 6;
    const int l15 = lane & 15;
    const int lg  = lane >> 4;
    const int wq  = w * 16;

    // bijective XCD swizzle: 1536 blocks, 192 per XCD = 12 whole b's
    const int bid = blockIdx.x;
    const int swz = (bid & 7) * 192 + (bid >> 3);
    const int b = swz >> 4;
    const int qbase = (swz & 15) * 64;

    // ---- prologue: Q -> qs (fp32, exact, for bias dot products)
    {
        const int row = t >> 2;
        const int c0 = (t & 3) * 16;
        const float* src = qf + ((size_t)b * HW_ + qbase + row) * HD_ + c0;
        #pragma unroll
        for (int u = 0; u < 4; ++u) {
            float4 v4 = *(const float4*)(src + u * 4);
            float* qd = qs + row * 68 + c0 + u * 4;
            qd[0] = v4.x; qd[1] = v4.y; qd[2] = v4.z; qd[3] = v4.w;
        }
    }

    // ---- Q fragments straight from global (bf16, pre-scaled by SCALE_)
    s16x8 qa0, qa1;
    {
        const float* qrow = qf + ((size_t)b * HW_ + qbase + wq + l15) * HD_;
        float4 a0 = *(const float4*)(qrow + lg * 8);
        float4 a1 = *(const float4*)(qrow + lg * 8 + 4);
        float4 b0 = *(const float4*)(qrow + 32 + lg * 8);
        float4 b1 = *(const float4*)(qrow + 32 + lg * 8 + 4);
        qa0[0] = (short)f2b(a0.x * SCALE_); qa0[1] = (short)f2b(a0.y * SCALE_);
        qa0[2] = (short)f2b(a0.z * SCALE_); qa0[3] = (short)f2b(a0.w * SCALE_);
        qa0[4] = (short)f2b(a1.x * SCALE_); qa0[5] = (short)f2b(a1.y * SCALE_);
        qa0[6] = (short)f2b(a1.z * SCALE_); qa0[7] = (short)f2b(a1.w * SCALE_);
        qa1[0] = (short)f2b(b0.x * SCALE_); qa1[1] = (short)f2b(b0.y * SCALE_);
        qa1[2] = (short)f2b(b0.z * SCALE_); qa1[3] = (short)f2b(b0.w * SCALE_);
        qa1[4] = (short)f2b(b1.x * SCALE_); qa1[5] = (short)f2b(b1.y * SCALE_);
        qa1[6] = (short)f2b(b1.z * SCALE_); qa1[7] = (short)f2b(b1.w * SCALE_);
    }
    __syncthreads();   // qs ready

    // ---- bias tables: bh -> bf16 LDS (persistent); bw -> f32 transient
    for (int idv = t; idv < 4096; idv += 256) {
        const int table = idv >> 11;
        const int rem = idv & 2047;
        const int row = rem >> 5;
        const int j   = rem & 31;
        const int qrow = qbase + row;
        const float* rp = (table == 0)
            ? rel_h + (size_t)((qrow >> 5) - j + 31) * HD_
            : rel_w + (size_t)((qrow & 31) - j + 31) * HD_;
        const float* qv = qs + row * 68;
        float acc = 0.f;
        #pragma unroll
        for (int d4 = 0; d4 < 16; ++d4) {
            float4 r4 = *(const float4*)(rp + d4 * 4);
            acc += qv[d4*4+0]*r4.x + qv[d4*4+1]*r4.y + qv[d4*4+2]*r4.z + qv[d4*4+3]*r4.w;
        }
        if (table == 0) sBHu[row * 34 + j] = f2b(acc);
        else            sBW[row * 36 + j] = acc;
    }
    __syncthreads();    // tables ready; qs dead after this barrier

    // ---- hoist bw to f32 registers (this lane's q row = wq + l15)
    const f32x4 bwE = *(const f32x4*)(sBW + (wq + l15) * 36 + lg * 4);
    const f32x4 bwO = *(const f32x4*)(sBW + (wq + l15) * 36 + 16 + lg * 4);

    // ---- staging geometry (round-6 verified mapping)
    const int srow = t >> 2;
    const int sc0  = (t & 3) * 16;
    const u16* kg = kbf + (size_t)b * HW_ * HD_ + (size_t)srow * HD_ + sc0;
    const u16* vg = vtb + (size_t)b * HD_ * HW_ + (size_t)srow * HW_ + sc0;
    u16* skw = sK  + srow * 72 + sc0;
    u16* svw = sVt + srow * 72 + sc0;

    // ---- preload tile 0 (K and V)
    s16x8 kr0 = *(const s16x8*)(kg);
    s16x8 kr1 = *(const s16x8*)(kg + 8);
    s16x8 vr0 = *(const s16x8*)(vg);
    s16x8 vr1 = *(const s16x8*)(vg + 8);
    *(s16x8*)(skw)     = kr0;
    *(s16x8*)(skw + 8) = kr1;
    *(s16x8*)(svw)     = vr0;
    *(s16x8*)(svw + 8) = vr1;
    __syncthreads();   // sK(0)/sVt(0) ready

    f32x4 Oacc[4] = {};
    float lsum = 0.f;
    const int srcA = l15 + 32 * (lg & 1);
    const int srcB = srcA + 16;
    const bool hiSel = (lg >> 1) != 0;
    const int bhbase = (wq + l15) * 34;

    for (int kt = 0; kt < 16; ++kt) {
        // ---- issue K(kt+1)/V(kt+1) global loads (drained at B1 by compiler)
        if (kt < 15) {
            const u16* kn = kg + (size_t)(kt + 1) * 64 * HD_;
            kr0 = *(const s16x8*)(kn);
            kr1 = *(const s16x8*)(kn + 8);
            const u16* vn = vg + (size_t)(kt + 1) * 64;
            vr0 = *(const s16x8*)(vn);
            vr1 = *(const s16x8*)(vn + 8);
        }

        const float bhA = b2f(sBHu[bhbase + 2 * kt]);
        const float bhB = b2f(sBHu[bhbase + 2 * kt + 1]);

        // ---- S^T = K Q^T (swapped): lane holds S[q=wq+l15][kv=nb*16+lg*4+r]
        u32x2 pw[4];
        #pragma unroll
        for (int nb = 0; nb < 4; ++nb) {
            const u16* kp = sK + (nb * 16 + l15) * 72 + lg * 8;
            s16x8 kf0 = *(const s16x8*)(kp);
            s16x8 kf1 = *(const s16x8*)(kp + 32);
            f32x4 s = {0.f, 0.f, 0.f, 0.f};
            s = __builtin_amdgcn_mfma_f32_16x16x32_bf16(kf0, qa0, s, 0, 0, 0);
            s = __builtin_amdgcn_mfma_f32_16x16x32_bf16(kf1, qa1, s, 0, 0, 0);
            const float bh = (nb >> 1) ? bhB : bhA;
            const f32x4 bw = (nb & 1) ? bwO : bwE;
            float p0 = __expf(s[0] + bh + bw[0]);
            float p1 = __expf(s[1] + bh + bw[1]);
            float p2 = __expf(s[2] + bh + bw[2]);
            float p3 = __expf(s[3] + bh + bw[3]);
            lsum += (p0 + p1) + (p2 + p3);
            pw[nb].x = (u32)f2b(p0) | ((u32)f2b(p1) << 16);
            pw[nb].y = (u32)f2b(p2) | ((u32)f2b(p3) << 16);
        }

        // ---- PV: A-fragment via in-register shfl redistribution
        #pragma unroll
        for (int kvh = 0; kvh < 2; ++kvh) {
            int a0 = __shfl((int)pw[2 * kvh].x,     srcA);
            int c0_ = __shfl((int)pw[2 * kvh + 1].x, srcA);
            int a1 = __shfl((int)pw[2 * kvh].y,     srcA);
            int c1_ = __shfl((int)pw[2 * kvh + 1].y, srcA);
            int a2 = __shfl((int)pw[2 * kvh].x,     srcB);
            int c2_ = __shfl((int)pw[2 * kvh + 1].x, srcB);
            int a3 = __shfl((int)pw[2 * kvh].y,     srcB);
            int c3_ = __shfl((int)pw[2 * kvh + 1].y, srcB);
            u32x4 pau;
            pau.x = hiSel ? (u32)c0_ : (u32)a0;
            pau.y = hiSel ? (u32)c1_ : (u32)a1;
            pau.z = hiSel ? (u32)c2_ : (u32)a2;
            pau.w = hiSel ? (u32)c3_ : (u32)a3;
            s16x8 pa = *reinterpret_cast<s16x8*>(&pau);
            #pragma unroll
            for (int db = 0; db < 4; ++db) {
                s16x8 vbx = *(const s16x8*)(sVt + (db * 16 + l15) * 72 + kvh * 32 + lg * 8);
                Oacc[db] = __builtin_amdgcn_mfma_f32_16x16x32_bf16(pa, vbx, Oacc[db], 0, 0, 0);
            }
        }

        __syncthreads();   // B1: all waves done reading sK/sVt(kt); prefetch drained
        if (kt < 15) {
            *(s16x8*)(skw)     = kr0;
            *(s16x8*)(skw + 8) = kr1;
            *(s16x8*)(svw)     = vr0;
            *(s16x8*)(svw + 8) = vr1;
        }
        __syncthreads();   // B2: sK/sVt(kt+1) visible
    }

    // ---- epilogue: lane's lsum is a partial for q = wq+l15
    float lsumF = lsum;
    lsumF += __shfl_xor(lsumF, 16);
    lsumF += __shfl_xor(lsumF, 32);
    float linv[4];
    #pragma unroll
    for (int r = 0; r < 4; ++r)
        linv[r] = 1.0f / __shfl(lsumF, lg * 4 + r, 16);

    const int n_img = b / NH_;
    const int head  = b % NH_;
    #pragma unroll
    for (int db = 0; db < 4; ++db) {
        #pragma unroll
        for (int r = 0; r < 4; ++r) {
            const int qg = qbase + wq + lg * 4 + r;
            ob[(size_t)(n_img * HW_ + qg) * C_ + head * HD_ + db * 16 + l15] =
                f2b(Oacc[db][r] * linv[r]);
        }
    }
}

extern "C" void kernel_launch(void* const* d_in, const int* in_sizes, int n_in,
                              void* d_out, int out_size, void* d_ws, size_t ws_size,
                              hipStream_t stream) {
    const float* x      = (const float*)d_in[0];
    const float* w_qkv  = (const float*)d_in[1];
    const float* b_qkv  = (const float*)d_in[2];
    const float* w_proj = (const float*)d_in[3];
    const float* b_proj = (const float*)d_in[4];
    const float* rel_h  = (const float*)d_in[5];
    const float* rel_w  = (const float*)d_in[6];
    float* out = (float*)d_out;

    const size_t seg = (size_t)B_ * HW_ * HD_;   // 6,291,456
    char* p = (char*)d_ws;
    u16* xb     = (u16*)p;  p += seg * 2;
    u16* wqkvT  = (u16*)p;  p += (size_t)C3_ * C_ * 2;
    u16* wprojT = (u16*)p;  p += (size_t)C_ * C_ * 2;
    float* qfp  = (float*)p; p += seg * 4;
    u16* kbf    = (u16*)p;  p += seg * 2;
    u16* vtb    = (u16*)p;  p += seg * 2;
    u16* ob     = (u16*)p;  p += seg * 2;

    cvt_bf16<<<2048, 256, 0, stream>>>(x, xb, (int)(seg / 4));
    tcvt_bf16<<<dim3(C3_ / 64, C_ / 64), 256, 0, stream>>>(w_qkv, wqkvT, C_, C3_);
    tcvt_bf16<<<dim3(C_ / 64, C_ / 64), 256, 0, stream>>>(w_proj, wprojT, C_, C_);

    gemm_qkv<<<dim3(C3_ / 128, 8192 / 128), 256, 0, stream>>>(xb, wqkvT, b_qkv, qfp, kbf, vtb);
    attn_mfma<<<1536, 256, 32000, stream>>>(qfp, kbf, vtb, rel_h, rel_w, ob);
    gemm_proj<<<dim3(C_ / 128, 8192 / 128), 256, 0, stream>>>(ob, wprojT, b_proj, out);
}

// Round 10
// 318.813 us; speedup vs baseline: 1.0775x; 1.0775x over previous
//
#include <hip/hip_runtime.h>
#include <hip/hip_bf16.h>

#define N_    8
#define H_    32
#define W_    32
#define C_    768
#define NH_   12
#define HD_   64
#define B_    96      // N_*NH_
#define HW_   1024
#define C3_   2304
#define SCALE_ 0.125f
#define LOG2E_ 1.4426950408889634f

typedef __attribute__((ext_vector_type(4))) float f32x4;
typedef __attribute__((ext_vector_type(16))) float f32x16;
typedef __attribute__((ext_vector_type(8))) short s16x8;
typedef __attribute__((ext_vector_type(2))) int i32x2;
typedef __attribute__((ext_vector_type(4))) unsigned int u32x4;
typedef unsigned short u16;
typedef unsigned int u32;

__device__ inline u16 f2b(float x) {
    __hip_bfloat16 h = __float2bfloat16(x);
    return *reinterpret_cast<u16*>(&h);
}
__device__ inline float b2f(u16 x) {
    u32 u = ((u32)x) << 16;
    return *reinterpret_cast<float*>(&u);
}

__device__ __forceinline__ void gld_lds16(const void* g, void* l) {
    __builtin_amdgcn_global_load_lds(
        (const __attribute__((address_space(1))) u32*)g,
        (__attribute__((address_space(3))) u32*)l, 16, 0, 0);
}

// ---------------------------------------------------------------------------
// convert fp32 -> bf16 (vectorized, grid-stride)
// ---------------------------------------------------------------------------
__global__ __launch_bounds__(256) void cvt_bf16(const float* __restrict__ in,
                                                u16* __restrict__ out, int n4) {
    for (int i = blockIdx.x * blockDim.x + threadIdx.x; i < n4; i += gridDim.x * blockDim.x) {
        float4 v = ((const float4*)in)[i];
        ushort4 o;
        o.x = f2b(v.x); o.y = f2b(v.y); o.z = f2b(v.z); o.w = f2b(v.w);
        ((ushort4*)out)[i] = o;
    }
}

// ---------------------------------------------------------------------------
// transpose-convert: in [K][N] fp32 -> out [N][K] bf16, 64x64 tiles
// ---------------------------------------------------------------------------
__global__ __launch_bounds__(256) void tcvt_bf16(const float* __restrict__ in,
                                                 u16* __restrict__ out, int K, int N) {
    __shared__ u16 tile[64][72];
    const int t = threadIdx.x;
    const int k0 = blockIdx.y * 64, n0 = blockIdx.x * 64;
    const int r = t >> 2, c4 = (t & 3) * 16;
    #pragma unroll
    for (int u = 0; u < 4; ++u) {
        float4 v = *(const float4*)(in + (size_t)(k0 + r) * N + n0 + c4 + u * 4);
        tile[c4 + u*4 + 0][r] = f2b(v.x);
        tile[c4 + u*4 + 1][r] = f2b(v.y);
        tile[c4 + u*4 + 2][r] = f2b(v.z);
        tile[c4 + u*4 + 3][r] = f2b(v.w);
    }
    __syncthreads();
    #pragma unroll
    for (int u = 0; u < 2; ++u) {
        s16x8 v;
        #pragma unroll
        for (int e = 0; e < 8; ++e) v[e] = (short)tile[r][c4 + u*8 + e];
        *(s16x8*)(out + (size_t)(n0 + r) * K + k0 + c4 + u*8) = v;
    }
}

// ---------------------------------------------------------------------------
// MFMA GEMM core (m97-style): 128x128 tile, BK=32, 4 waves 2x2, double-buffered
// LDS via global_load_lds width 16, one barrier per K-step. K = 768.
// ---------------------------------------------------------------------------
#define GEMM_CORE(A_, Bt_)                                                           \
    __shared__ u16 sA[2][128 * 32];                                                  \
    __shared__ u16 sB[2][128 * 32];                                                  \
    const int t = threadIdx.x;                                                       \
    const int lane = t & 63;                                                         \
    const int w = t >> 6;                                                            \
    const int wm = w >> 1, wn = w & 1;                                               \
    const int l15 = lane & 15, lg = lane >> 4;                                       \
    const int nbase = blockIdx.x * 128;                                              \
    const int mbase = blockIdx.y * 128;                                              \
    const int srow = lane >> 2;                                                      \
    const int sslot = lane & 3;                                                      \
    const u16* gA0 = (A_) + (size_t)(mbase + w * 16 + srow) * 768 + sslot * 8;       \
    const u16* gA1 = gA0 + (size_t)64 * 768;                                         \
    const u16* gB0 = (Bt_) + (size_t)(nbase + w * 16 + srow) * 768 + sslot * 8;      \
    const u16* gB1 = gB0 + (size_t)64 * 768;                                         \
    f32x4 acc[4][4] = {};                                                            \
    gld_lds16(gA0, &sA[0][w * 512]);                                                 \
    gld_lds16(gA1, &sA[0][(w + 4) * 512]);                                           \
    gld_lds16(gB0, &sB[0][w * 512]);                                                 \
    gld_lds16(gB1, &sB[0][(w + 4) * 512]);                                           \
    for (int kt = 0; kt < 24; ++kt) {                                                \
        const int p = kt & 1;                                                        \
        __syncthreads();                                                             \
        if (kt < 23) {                                                               \
            const int kb = (kt + 1) * 32;                                            \
            gld_lds16(gA0 + kb, &sA[p ^ 1][w * 512]);                                \
            gld_lds16(gA1 + kb, &sA[p ^ 1][(w + 4) * 512]);                          \
            gld_lds16(gB0 + kb, &sB[p ^ 1][w * 512]);                                \
            gld_lds16(gB1 + kb, &sB[p ^ 1][(w + 4) * 512]);                          \
        }                                                                            \
        const u16* pa = &sA[p][(wm * 64 + l15) * 32 + lg * 8];                       \
        const u16* pb = &sB[p][(wn * 64 + l15) * 32 + lg * 8];                       \
        s16x8 afr[4], bfr[4];                                                        \
        _Pragma("unroll")                                                            \
        for (int i = 0; i < 4; ++i) {                                                \
            afr[i] = *(const s16x8*)(pa + i * 512);                                  \
            bfr[i] = *(const s16x8*)(pb + i * 512);                                  \
        }                                                                            \
        _Pragma("unroll")                                                            \
        for (int i = 0; i < 4; ++i)                                                  \
            _Pragma("unroll")                                                        \
            for (int j = 0; j < 4; ++j)                                              \
                acc[i][j] = __builtin_amdgcn_mfma_f32_16x16x32_bf16(afr[i], bfr[j],  \
                                                                    acc[i][j], 0, 0, 0); \
    }

__global__ __launch_bounds__(256) void gemm_qkv(const u16* __restrict__ A,
                                                const u16* __restrict__ Bt,
                                                const float* __restrict__ bias,
                                                float* __restrict__ qout,
                                                u16* __restrict__ kout,
                                                u16* __restrict__ vout) {
    GEMM_CORE(A, Bt)
    const int which = nbase / C_;
    const int head  = ((nbase % C_) >> 6) + wn;
    const int mrow0 = mbase + wm * 64 + lg * 4;
    #pragma unroll
    for (int i = 0; i < 4; ++i) {
        #pragma unroll
        for (int r = 0; r < 4; ++r) {
            const int m = mrow0 + i * 16 + r;
            const size_t bidx = (size_t)((m >> 10) * NH_ + head);
            const int pp = m & 1023;
            #pragma unroll
            for (int j = 0; j < 4; ++j) {
                const int d = j * 16 + l15;
                const float val = acc[i][j][r] + bias[nbase + wn * 64 + d];
                if (which == 0)      qout[(bidx * HW_ + pp) * HD_ + d] = val;
                else if (which == 1) kout[(bidx * HW_ + pp) * HD_ + d] = f2b(val);
                else                 vout[bidx * (size_t)(HW_ * HD_) + (size_t)d * HW_ + pp] = f2b(val);
            }
        }
    }
}

__global__ __launch_bounds__(256) void gemm_proj(const u16* __restrict__ A,
                                                 const u16* __restrict__ Bt,
                                                 const float* __restrict__ bias,
                                                 float* __restrict__ out) {
    GEMM_CORE(A, Bt)
    const int mrow0 = mbase + wm * 64 + lg * 4;
    #pragma unroll
    for (int i = 0; i < 4; ++i) {
        #pragma unroll
        for (int r = 0; r < 4; ++r) {
            const int m = mrow0 + i * 16 + r;
            #pragma unroll
            for (int j = 0; j < 4; ++j) {
                const int n = nbase + wn * 64 + j * 16 + l15;
                out[(size_t)m * C_ + n] = acc[i][j][r] + bias[n];
            }
        }
    }
}

// ---------------------------------------------------------------------------
// Kernel: MFMA bf16 flash rel-pos attention — 32x32 MFMA + in-register P.
// Block: 4 waves x 32 q-rows = 128 q; grid 768 = 96 b x 8 q-tiles (3-4/CU).
// Swapped QK^T (32x32x16): lane l holds S[kv-regs][q = l&31]; kv(reg r) =
// kvt*32 + (r&3) + 8*(r>>2) + 4*(l>>5)   [D layout verified, guide m74/m101].
// PV A-frag built IN REGISTER: 16 manual bf16 packs + 8 permlane32_swap
// (pairs (pw[m], pw[m+2]) per the T12 recipe; o0={a.lo,b.lo}, o1={a.hi,b.hi}).
// exp2-folded softmax: Q pre-scaled by SCALE*log2e, bias tables by log2e ->
// one v_exp_f32 per element.  bw bias (iter-invariant) hoisted to 16 regs;
// bh in bf16 LDS table (conflict-free).  Max-free softmax as rounds 2-9.
// K/V staged to LDS padded [64][72] (r8-verified mapping), reg-staged
// prefetch, 2 barriers per 64-kv tile.
// LDS map (bytes): sBH u16[128][34] @0 (8704, persistent);
//   sK u16[64][72] @8704; sVt u16[64][72] @17920 (end 27136);
//   qs f32[64][68] @8704 (transient, 2 passes); sBW f32[64][36] @27136 (9216).
// total 36352 -> 4 blocks/CU = 16 waves/CU.
// ---------------------------------------------------------------------------
__global__ __launch_bounds__(256, 4) void attn_mfma(const float* __restrict__ qf,
                                                    const u16* __restrict__ kbf,
                                                    const u16* __restrict__ vtb,
                                                    const float* __restrict__ rel_h,
                                                    const float* __restrict__ rel_w,
                                                    u16* __restrict__ ob) {
    extern __shared__ char smem[];
    u16*   sBH = (u16*)smem;                  // [128][34] bf16 (persistent)
    u16*   sK  = (u16*)(smem + 8704);         // [64][72]
    u16*   sVt = (u16*)(smem + 17920);        // [64][72]
    float* qs  = (float*)(smem + 8704);       // [64][68] f32 (prologue only)
    float* sBW = (float*)(smem + 27136);      // [64][36] f32 (prologue only)

    const int t = threadIdx.x;
    const int lane = t & 63;
    const int w = t >> 6;
    const int l31 = lane & 31;
    const int hi  = lane >> 5;
    const int qw  = w * 32;

    // XCD-bijective swizzle: 768 blocks, 96 per XCD = 12 whole b's
    const int bid = blockIdx.x;
    const int swz = (bid & 7) * 96 + (bid >> 3);
    const int b = swz >> 3;
    const int qbase = (swz & 7) * 128;

    // ---- Q fragments (B-operand of swapped QK^T): lane holds
    // Q[q = qw+l31][d = ck*16 + hi*8 + j], pre-scaled by SCALE*log2e.
    s16x8 qfr[4];
    {
        const float* qrow = qf + ((size_t)b * HW_ + qbase + qw + l31) * HD_;
        #pragma unroll
        for (int ck = 0; ck < 4; ++ck) {
            float4 x0 = *(const float4*)(qrow + ck * 16 + hi * 8);
            float4 x1 = *(const float4*)(qrow + ck * 16 + hi * 8 + 4);
            qfr[ck][0] = (short)f2b(x0.x * (SCALE_ * LOG2E_));
            qfr[ck][1] = (short)f2b(x0.y * (SCALE_ * LOG2E_));
            qfr[ck][2] = (short)f2b(x0.z * (SCALE_ * LOG2E_));
            qfr[ck][3] = (short)f2b(x0.w * (SCALE_ * LOG2E_));
            qfr[ck][4] = (short)f2b(x1.x * (SCALE_ * LOG2E_));
            qfr[ck][5] = (short)f2b(x1.y * (SCALE_ * LOG2E_));
            qfr[ck][6] = (short)f2b(x1.z * (SCALE_ * LOG2E_));
            qfr[ck][7] = (short)f2b(x1.w * (SCALE_ * LOG2E_));
        }
    }

    // ---- bias tables in two 64-row passes (x log2e); bw hoisted to regs.
    // bwv[m][j] = bw[q][m*8 + 4*hi + j]  (kw(reg r) = (r&3)+8*(r>>2)+4*hi).
    f32x4 bwv[4];
    for (int p = 0; p < 2; ++p) {
        {   // stage qs rows [p*64, p*64+64) (fp32, exact)
            const int row = t >> 2;
            const int c0 = (t & 3) * 16;
            const float* src = qf + ((size_t)b * HW_ + qbase + p * 64 + row) * HD_ + c0;
            #pragma unroll
            for (int u = 0; u < 4; ++u) {
                float4 v4 = *(const float4*)(src + u * 4);
                float* qd = qs + row * 68 + c0 + u * 4;
                qd[0] = v4.x; qd[1] = v4.y; qd[2] = v4.z; qd[3] = v4.w;
            }
        }
        __syncthreads();
        for (int idv = t; idv < 4096; idv += 256) {
            const int table = idv >> 11;
            const int rem = idv & 2047;
            const int row = rem >> 5;
            const int j   = rem & 31;
            const int qrow = qbase + p * 64 + row;
            const float* rp = (table == 0)
                ? rel_h + (size_t)((qrow >> 5) - j + 31) * HD_
                : rel_w + (size_t)((qrow & 31) - j + 31) * HD_;
            const float* qv = qs + row * 68;
            float acc = 0.f;
            #pragma unroll
            for (int d4 = 0; d4 < 16; ++d4) {
                float4 r4 = *(const float4*)(rp + d4 * 4);
                acc += qv[d4*4+0]*r4.x + qv[d4*4+1]*r4.y + qv[d4*4+2]*r4.z + qv[d4*4+3]*r4.w;
            }
            acc *= LOG2E_;
            if (table == 0) sBH[(p * 64 + row) * 34 + j] = f2b(acc);
            else            sBW[row * 36 + j] = acc;
        }
        __syncthreads();
        if ((w >> 1) == p) {
            const int qloc = (w & 1) * 32 + l31;
            #pragma unroll
            for (int m = 0; m < 4; ++m)
                bwv[m] = *(const f32x4*)(sBW + qloc * 36 + m * 8 + hi * 4);
        }
        __syncthreads();
    }

    // ---- staging geometry (r8-verified mapping, pad-72 rows)
    const int srow = t >> 2;
    const int sc0  = (t & 3) * 16;
    const u16* kg = kbf + (size_t)b * HW_ * HD_ + (size_t)srow * HD_ + sc0;
    const u16* vg = vtb + (size_t)b * HD_ * HW_ + (size_t)srow * HW_ + sc0;
    u16* skw = sK  + srow * 72 + sc0;
    u16* svw = sVt + srow * 72 + sc0;

    // ---- preload tile 0
    s16x8 kr0 = *(const s16x8*)(kg);
    s16x8 kr1 = *(const s16x8*)(kg + 8);
    s16x8 vr0 = *(const s16x8*)(vg);
    s16x8 vr1 = *(const s16x8*)(vg + 8);
    *(s16x8*)(skw)     = kr0;
    *(s16x8*)(skw + 8) = kr1;
    *(s16x8*)(svw)     = vr0;
    *(s16x8*)(svw + 8) = vr1;
    __syncthreads();   // sK(0)/sVt(0) ready

    f32x16 Oacc[2] = {};
    float lsum = 0.f;
    const int bhbase = (qw + l31) * 34;

    for (int kt = 0; kt < 16; ++kt) {
        // ---- issue prefetch for kt+1 (drained by the implicit vmcnt at B1)
        if (kt < 15) {
            const u16* kn = kg + (size_t)(kt + 1) * 64 * HD_;
            kr0 = *(const s16x8*)(kn);
            kr1 = *(const s16x8*)(kn + 8);
            const u16* vn = vg + (size_t)(kt + 1) * 64;
            vr0 = *(const s16x8*)(vn);
            vr1 = *(const s16x8*)(vn + 8);
        }

        const float bh0 = b2f(sBH[bhbase + 2 * kt]);
        const float bh1 = b2f(sBH[bhbase + 2 * kt + 1]);

        #pragma unroll
        for (int kvt = 0; kvt < 2; ++kvt) {
            // ---- S^T tile (32 kv x 32 q): acc over 4 d-chunks
            f32x16 s = {};
            #pragma unroll
            for (int ck = 0; ck < 4; ++ck) {
                s16x8 kf = *(const s16x8*)(sK + (kvt * 32 + l31) * 72 + ck * 16 + hi * 8);
                s = __builtin_amdgcn_mfma_f32_32x32x16_bf16(kf, qfr[ck], s, 0, 0, 0);
            }
            const float bh = kvt ? bh1 : bh0;

            // ---- exp2 + pack to bf16 pairs (kv(2m),kv(2m+1) consecutive)
            u32 pw[8];
            #pragma unroll
            for (int m = 0; m < 8; ++m) {
                float p0 = __builtin_amdgcn_exp2f(s[2*m]   + bh + bwv[(2*m)>>2][(2*m)&3]);
                float p1 = __builtin_amdgcn_exp2f(s[2*m+1] + bh + bwv[(2*m+1)>>2][(2*m+1)&3]);
                lsum += p0 + p1;
                pw[m] = (u32)f2b(p0) | ((u32)f2b(p1) << 16);
            }

            // ---- PV: A-frag via permlane32_swap, B-frag = Vt rows
            #pragma unroll
            for (int cc = 0; cc < 2; ++cc) {
                i32x2 s02 = __builtin_amdgcn_permlane32_swap((int)pw[cc*4+0], (int)pw[cc*4+2], false, false);
                i32x2 s13 = __builtin_amdgcn_permlane32_swap((int)pw[cc*4+1], (int)pw[cc*4+3], false, false);
                u32x4 pau;
                pau.x = (u32)s02.x; pau.y = (u32)s13.x;
                pau.z = (u32)s02.y; pau.w = (u32)s13.y;
                s16x8 pa = *reinterpret_cast<s16x8*>(&pau);
                const int kc = kvt * 2 + cc;          // kv chunk of 16
                #pragma unroll
                for (int dt = 0; dt < 2; ++dt) {
                    s16x8 vf = *(const s16x8*)(sVt + (dt * 32 + l31) * 72 + kc * 16 + hi * 8);
                    Oacc[dt] = __builtin_amdgcn_mfma_f32_32x32x16_bf16(pa, vf, Oacc[dt], 0, 0, 0);
                }
            }
        }

        __syncthreads();   // B1: all waves done reading sK/sVt(kt); prefetch landed
        if (kt < 15) {
            *(s16x8*)(skw)     = kr0;
            *(s16x8*)(skw + 8) = kr1;
            *(s16x8*)(svw)     = vr0;
            *(s16x8*)(svw + 8) = vr1;
        }
        __syncthreads();   // B2: sK/sVt(kt+1) visible
    }

    // ---- epilogue: lsum holds partials for q = qw + l31 (lane & partner)
    float lsumF = lsum + __shfl_xor(lsum, 32);
    float linv[16];
    #pragma unroll
    for (int r = 0; r < 16; ++r) {
        const int qloc = (r & 3) + 8 * (r >> 2) + 4 * hi;
        linv[r] = 1.0f / __shfl(lsumF, qloc);
    }

    const int n_img = b / NH_;
    const int head  = b % NH_;
    #pragma unroll
    for (int dt = 0; dt < 2; ++dt) {
        #pragma unroll
        for (int r = 0; r < 16; ++r) {
            const int qloc = (r & 3) + 8 * (r >> 2) + 4 * hi;
            const int qg = qbase + qw + qloc;
            ob[(size_t)(n_img * HW_ + qg) * C_ + head * HD_ + dt * 32 + l31] =
                f2b(Oacc[dt][r] * linv[r]);
        }
    }
}

extern "C" void kernel_launch(void* const* d_in, const int* in_sizes, int n_in,
                              void* d_out, int out_size, void* d_ws, size_t ws_size,
                              hipStream_t stream) {
    const float* x      = (const float*)d_in[0];
    const float* w_qkv  = (const float*)d_in[1];
    const float* b_qkv  = (const float*)d_in[2];
    const float* w_proj = (const float*)d_in[3];
    const float* b_proj = (const float*)d_in[4];
    const float* rel_h  = (const float*)d_in[5];
    const float* rel_w  = (const float*)d_in[6];
    float* out = (float*)d_out;

    const size_t seg = (size_t)B_ * HW_ * HD_;   // 6,291,456
    char* p = (char*)d_ws;
    u16* xb     = (u16*)p;  p += seg * 2;
    u16* wqkvT  = (u16*)p;  p += (size_t)C3_ * C_ * 2;
    u16* wprojT = (u16*)p;  p += (size_t)C_ * C_ * 2;
    float* qfp  = (float*)p; p += seg * 4;
    u16* kbf    = (u16*)p;  p += seg * 2;
    u16* vtb    = (u16*)p;  p += seg * 2;
    u16* ob     = (u16*)p;  p += seg * 2;

    cvt_bf16<<<2048, 256, 0, stream>>>(x, xb, (int)(seg / 4));
    tcvt_bf16<<<dim3(C3_ / 64, C_ / 64), 256, 0, stream>>>(w_qkv, wqkvT, C_, C3_);
    tcvt_bf16<<<dim3(C_ / 64, C_ / 64), 256, 0, stream>>>(w_proj, wprojT, C_, C_);

    gemm_qkv<<<dim3(C3_ / 128, 8192 / 128), 256, 0, stream>>>(xb, wqkvT, b_qkv, qfp, kbf, vtb);
    attn_mfma<<<768, 256, 36352, stream>>>(qfp, kbf, vtb, rel_h, rel_w, ob);
    gemm_proj<<<dim3(C_ / 128, 8192 / 128), 256, 0, stream>>>(ob, wprojT, b_proj, out);
}